// Round 1
// baseline (380.616 us; speedup 1.0000x reference)
//
#include <hip/hip_runtime.h>

// out[b,t,d] = sum_u (sum_d' X[b,t,d']*W[u,d'] / 32) * W[u,d]
//            = X · M,  M = (W^T W) / 32   (M is symmetric 1024x1024)
// B=16, T=4096, D=UNITS=1024.  X: 65536x1024 fp32.  W: 1024x1024 fp32.

typedef unsigned short u16;
typedef unsigned int u32;
typedef __bf16 bf16x8 __attribute__((ext_vector_type(8)));
typedef float f32x4 __attribute__((ext_vector_type(4)));

// round-to-nearest-even fp32 -> bf16
__device__ __forceinline__ u16 f2bf(float f) {
  u32 u = __float_as_uint(f);
  u += 0x7fffu + ((u >> 16) & 1u);
  return (u16)(u >> 16);
}

// async global->LDS, 16B per lane; LDS dest = base + lane*16 (wave-uniform base)
__device__ __forceinline__ void gload_lds16(const void* g, void* l) {
  __builtin_amdgcn_global_load_lds((const __attribute__((address_space(1))) u32*)g,
                                   (__attribute__((address_space(3))) u32*)l,
                                   16, 0, 0);
}

// ---------------- kernel 1: M = (W^T W) * (1/32), fp32 accumulate, bf16 out ----
// grid (16,16), block 256. Each block computes a 64x64 tile of M.
__global__ __launch_bounds__(256) void compute_M(const float* __restrict__ W,
                                                 u16* __restrict__ Mb) {
  __shared__ float w1[32][64];
  __shared__ float w2[32][64];
  const int t = threadIdx.x;
  const int i0 = blockIdx.y * 64;
  const int j0 = blockIdx.x * 64;
  const int tx = t & 15, ty = t >> 4;
  float acc[4][4] = {};
  for (int u0 = 0; u0 < 1024; u0 += 32) {
    __syncthreads();
#pragma unroll
    for (int p = 0; p < 2; ++p) {
      int idx = p * 256 + t;
      int lu = idx >> 4, lc = (idx & 15) * 4;
      *(float4*)&w1[lu][lc] = *(const float4*)(W + (size_t)(u0 + lu) * 1024 + i0 + lc);
      *(float4*)&w2[lu][lc] = *(const float4*)(W + (size_t)(u0 + lu) * 1024 + j0 + lc);
    }
    __syncthreads();
#pragma unroll 8
    for (int u = 0; u < 32; ++u) {
      float4 a = *(const float4*)&w1[u][ty * 4];
      float4 b = *(const float4*)&w2[u][tx * 4];
      float av[4] = {a.x, a.y, a.z, a.w};
      float bv[4] = {b.x, b.y, b.z, b.w};
#pragma unroll
      for (int e = 0; e < 4; ++e)
#pragma unroll
        for (int f = 0; f < 4; ++f)
          acc[e][f] += av[e] * bv[f];
    }
  }
  const float s = 0.03125f;  // 1/sqrt(1024)
#pragma unroll
  for (int e = 0; e < 4; ++e) {
    ushort4 v;
    v.x = f2bf(acc[e][0] * s);
    v.y = f2bf(acc[e][1] * s);
    v.z = f2bf(acc[e][2] * s);
    v.w = f2bf(acc[e][3] * s);
    *(ushort4*)(Mb + (size_t)(i0 + ty * 4 + e) * 1024 + j0 + tx * 4) = v;
  }
}

// ---------------- kernel 2: out = Xbf16 · Mbf16 (bf16 MFMA, fp32 C) -----------
// 128x128 tile, BK=32, 256 threads (4 waves, 2x2), 16x16x32 bf16 MFMA.
// A (X fp32) reg-staged with fused cvt; B (M bf16) via global_load_lds with
// pre-swizzled source. Both LDS tiles use chunk-XOR swizzle:
//   chunk' = chunk ^ ((row>>1)&3)   (16B chunks, 4 per 64B row)
// -> ds_read_b128 of 16 consecutive rows hits 8 distinct bank-quads (2-way = free).
__global__ __launch_bounds__(256) void gemm_xm(const float* __restrict__ X,
                                               const u16* __restrict__ Mb,
                                               float* __restrict__ out) {
  __shared__ u16 lA[128 * 32];
  __shared__ u16 lB[128 * 32];

  // chunked XCD swizzle: nwg=4096, 8 XCDs -> XCD x owns bm in [64x,64x+64);
  // the 8 blocks sharing an A-panel (same bm) are consecutive on one XCD.
  const int p = blockIdx.x;
  const int wg = (p & 7) * 512 + (p >> 3);
  const int bm = wg >> 3;   // 0..511
  const int bn = wg & 7;    // 0..7
  const size_t r0 = (size_t)bm * 128;
  const int c0 = bn * 128;

  const int t = threadIdx.x;
  const int lane = t & 63;
  const int w = t >> 6;
  const int wr = w >> 1, wc = w & 1;  // 2x2 wave grid; wave tile 64x64

  // A staging: thread loads float4 of X at (row ar, cols ac*4..ac*4+3)
  const int ar_base = t >> 3;  // 0..31 (4 passes cover 128 rows)
  const int ac = t & 7;
  const int a_chunk = ac >> 1;
  const int a_half = ac & 1;

  // fragment read indices
  const int fr = lane & 15;  // row (A) / col (B) within 16
  const int kc = lane >> 4;  // k-chunk (8 contiguous bf16)

  f32x4 acc[4][4] = {};

  for (int k0 = 0; k0 < 1024; k0 += 32) {
    // ---- stage B: 8KB via 8 wave-calls of global_load_lds (2 per wave) ----
#pragma unroll
    for (int i = 0; i < 2; ++i) {
      const int slot0 = w * 128 + i * 64;       // wave-uniform
      const int slot = slot0 + lane;            // 0..511, lane writes slot*16
      const int nr = slot >> 2;                 // B row (output col index)
      const int cc = (slot & 3) ^ ((nr >> 1) & 3);  // inverse-swizzled src chunk
      const char* g = (const char*)(Mb + (size_t)(c0 + nr) * 1024 + k0) + cc * 16;
      gload_lds16(g, (void*)(lB + slot0 * 8));
    }
    // ---- stage A: 4 passes of float4 load + cvt + swizzled 8B ds_write ----
#pragma unroll
    for (int q = 0; q < 4; ++q) {
      const int ar = q * 32 + ar_base;
      const float4 v = *(const float4*)(X + (r0 + ar) * 1024 + k0 + ac * 4);
      uint2 d;
      d.x = (u32)f2bf(v.x) | ((u32)f2bf(v.y) << 16);
      d.y = (u32)f2bf(v.z) | ((u32)f2bf(v.w) << 16);
      const int cs = a_chunk ^ ((ar >> 1) & 3);
      *(uint2*)&lA[ar * 32 + cs * 8 + a_half * 4] = d;
    }
    __syncthreads();  // compiler emits vmcnt(0)+lgkmcnt(0) drain here
    // ---- compute: 8 ds_read_b128 + 16 MFMA ----
    bf16x8 afr[4], bfr[4];
#pragma unroll
    for (int m = 0; m < 4; ++m) {
      const int row = wr * 64 + m * 16 + fr;
      const int cs = kc ^ ((row >> 1) & 3);
      afr[m] = *(const bf16x8*)&lA[row * 32 + cs * 8];
    }
#pragma unroll
    for (int n = 0; n < 4; ++n) {
      const int row = wc * 64 + n * 16 + fr;
      const int cs = kc ^ ((row >> 1) & 3);
      bfr[n] = *(const bf16x8*)&lB[row * 32 + cs * 8];
    }
#pragma unroll
    for (int m = 0; m < 4; ++m)
#pragma unroll
      for (int n = 0; n < 4; ++n)
        acc[m][n] = __builtin_amdgcn_mfma_f32_16x16x32_bf16(afr[m], bfr[n],
                                                            acc[m][n], 0, 0, 0);
    __syncthreads();  // protect LDS before next stage overwrites
  }

  // ---- epilogue: C/D layout col=lane&15, row=(lane>>4)*4+reg ----
  const int ocol = lane & 15;
  const int orow = (lane >> 4) * 4;
#pragma unroll
  for (int m = 0; m < 4; ++m) {
    const size_t rbase = (r0 + wr * 64 + m * 16 + orow) * 1024;
#pragma unroll
    for (int n = 0; n < 4; ++n) {
      float* o = out + rbase + (c0 + wc * 64 + n * 16 + ocol);
      o[0] = acc[m][n][0];
      o[1024] = acc[m][n][1];
      o[2048] = acc[m][n][2];
      o[3072] = acc[m][n][3];
    }
  }
}

extern "C" void kernel_launch(void* const* d_in, const int* in_sizes, int n_in,
                              void* d_out, int out_size, void* d_ws, size_t ws_size,
                              hipStream_t stream) {
  const float* X = (const float*)d_in[0];   // (16,4096,1024) fp32
  const float* W = (const float*)d_in[1];   // (1024,1024) fp32
  float* out = (float*)d_out;               // (16,4096,1024) fp32
  u16* Mb = (u16*)d_ws;                     // 1024*1024 bf16 = 2MB scratch

  compute_M<<<dim3(16, 16), 256, 0, stream>>>(W, Mb);
  gemm_xm<<<4096, 256, 0, stream>>>(X, Mb, out);
}